// Round 2
// baseline (860.851 us; speedup 1.0000x reference)
//
#include <hip/hip_runtime.h>
#include <hip/hip_bf16.h>
#include <math.h>

#define NB 16
#define HIMG 128
#define WIMG 128
#define NTOK 16384
#define CDIM 192
#define CRDIM 96
#define NHEAD 8
#define HDIM 24
#define CRHD 12
#define MRED 64
#define SCALE_QK 0.28867513459481287f

typedef __bf16 bf16x8 __attribute__((ext_vector_type(8)));
typedef __bf16 bf16x4 __attribute__((ext_vector_type(4)));
typedef float f32x4 __attribute__((ext_vector_type(4)));

// ---------------- prep: convert v_w / proj_w to bf16 ----------------
__global__ void k_prep(const float* __restrict__ vw, const float* __restrict__ pw,
                       __bf16* __restrict__ wb) {
    int i = blockIdx.x * 256 + threadIdx.x;
    if (i < CRDIM * CDIM) wb[i] = (__bf16)vw[i];
    else if (i < CRDIM * CDIM + CDIM * CDIM) wb[i] = (__bf16)pw[i - CRDIM * CDIM];
}

// ---------------- K1: two stride-4 dw convs folded into effective 16x16 stride-16 ----------------
__global__ void k_reduce(const float* __restrict__ x, const float* __restrict__ rw,
                         const float* __restrict__ rb, float* __restrict__ y1) {
    int m = blockIdx.x;          // 0..63 output pixel (8x8)
    int b = blockIdx.y;
    int c = threadIdx.x;         // 0..191
    float w[16];
#pragma unroll
    for (int i = 0; i < 16; ++i) w[i] = rw[c * 16 + i];
    int py = m >> 3, px = m & 7;
    const float* xb = x + (long)b * NTOK * CDIM + c;
    float acc = 0.f;
    for (int a = 0; a < 16; ++a) {
        const float* xrow = xb + (long)((py * 16 + a) * WIMG + px * 16) * CDIM;
#pragma unroll
        for (int bb = 0; bb < 16; ++bb) {
            float coef = w[((a >> 2) << 2) + (bb >> 2)] * w[((a & 3) << 2) + (bb & 3)];
            acc += coef * xrow[(long)bb * CDIM];
        }
    }
    float S = 0.f;
#pragma unroll
    for (int i = 0; i < 16; ++i) S += w[i];
    acc += rb[c] * (S + 1.f);    // bias through both convs
    y1[(b * MRED + m) * CDIM + c] = acc;
}

// ---------------- K2: dw3x3 + 1x1 mix + LN + exact GELU ----------------
__global__ void k_dwmix(const float* __restrict__ y1, const float* __restrict__ dww,
                        const float* __restrict__ dwb, const float* __restrict__ cw,
                        const float* __restrict__ cb, const float* __restrict__ lg,
                        const float* __restrict__ lb, float* __restrict__ xr) {
    __shared__ float sT[CDIM];
    __shared__ float sU[CDIM];
    int m = blockIdx.x, b = blockIdx.y, c = threadIdx.x;
    int py = m >> 3, px = m & 7;
    float t = dwb[c];
#pragma unroll
    for (int ki = 0; ki < 3; ++ki)
#pragma unroll
        for (int kj = 0; kj < 3; ++kj) {
            int yy = py + ki - 1, xx = px + kj - 1;
            if (yy >= 0 && yy < 8 && xx >= 0 && xx < 8)
                t += dww[c * 9 + ki * 3 + kj] * y1[(b * MRED + yy * 8 + xx) * CDIM + c];
        }
    sT[c] = t;
    __syncthreads();
    float u = cb[c];
    for (int cc = 0; cc < CDIM; ++cc) u += cw[c * CDIM + cc] * sT[cc];
    sU[c] = u;
    __syncthreads();
    float s = 0.f, s2 = 0.f;
    for (int cc = 0; cc < CDIM; ++cc) { float vv = sU[cc]; s += vv; s2 += vv * vv; }
    float mu = s * (1.f / CDIM);
    float var = fmaxf(s2 * (1.f / CDIM) - mu * mu, 0.f);
    float xh = (u - mu) * rsqrtf(var + 1e-5f);
    float g = xh * lg[c] + lb[c];
    float ge = 0.5f * g * (1.f + erff(g * 0.70710678118654752440f));
    xr[(b * MRED + m) * CDIM + c] = ge;
}

// ---------------- K3a: q = xr@q_w^T, k = xr@k_w^T ----------------
__global__ void k_qk(const float* __restrict__ xr, const float* __restrict__ qw,
                     const float* __restrict__ kw, float* __restrict__ q,
                     float* __restrict__ k) {
    __shared__ float sx[8 * 193];
    int mg = blockIdx.x;   // 0..7 (group of 8 reduced tokens)
    int b = blockIdx.y;
    int tid = threadIdx.x;
    const float* src = xr + (b * MRED + mg * 8) * CDIM;
    for (int i = tid; i < 8 * CDIM; i += 256) sx[(i / CDIM) * 193 + (i % CDIM)] = src[i];
    __syncthreads();
    for (int oi = tid; oi < 1536 + 768; oi += 256) {
        if (oi < 1536) {
            int d = oi >> 3, mi = oi & 7;
            const float* wr = qw + d * CDIM;
            const float* xs = sx + mi * 193;
            float acc = 0.f;
            for (int c = 0; c < CDIM; ++c) acc += xs[c] * wr[c];
            q[(b * MRED + mg * 8 + mi) * CDIM + d] = acc;
        } else {
            int oj = oi - 1536;
            int e = oj >> 3, mi = oj & 7;
            const float* wr = kw + e * CDIM;
            const float* xs = sx + mi * 193;
            float acc = 0.f;
            for (int c = 0; c < CDIM; ++c) acc += xs[c] * wr[c];
            k[(b * MRED + mg * 8 + mi) * CRDIM + e] = acc;
        }
    }
}

// ---------------- K3b: logits over m (64) + softmax over e (12) ----------------
__global__ void k_attn(const float* __restrict__ q, const float* __restrict__ k,
                       float* __restrict__ attn) {
    __shared__ float sL[HDIM * CRHD];
    int h = blockIdx.x, b = blockIdx.y;
    int tid = threadIdx.x;
    for (int i = tid; i < HDIM * CRHD; i += 256) {
        int d = i / CRHD, e = i % CRHD;
        float acc = 0.f;
        for (int m = 0; m < MRED; ++m)
            acc += q[(b * MRED + m) * CDIM + h * HDIM + d] *
                   k[(b * MRED + m) * CRDIM + h * CRHD + e];
        sL[i] = acc * SCALE_QK;
    }
    __syncthreads();
    if (tid < HDIM) {
        float mx = -1e30f;
#pragma unroll
        for (int e = 0; e < CRHD; ++e) mx = fmaxf(mx, sL[tid * CRHD + e]);
        float ex[CRHD]; float sum = 0.f;
#pragma unroll
        for (int e = 0; e < CRHD; ++e) { ex[e] = expf(sL[tid * CRHD + e] - mx); sum += ex[e]; }
        float inv = 1.f / sum;
#pragma unroll
        for (int e = 0; e < CRHD; ++e)
            attn[((b * NHEAD + h) * HDIM + tid) * CRHD + e] = ex[e] * inv;
    }
}

// ---------------- MFMA GEMM: C[rows,NOUT] = A[rows,192] @ W[NOUT,192]^T (+bias) ----------------
// rows = 262144 total, 64-row tiles. 4 waves, each 1 M-frag x NF N-frags, K=6x32.
template <int NOUT, bool ABF16, bool OUTBF16, bool BIAS>
__global__ __launch_bounds__(256) void k_gemm(const void* __restrict__ Asrc,
                                              const __bf16* __restrict__ Wb,
                                              const float* __restrict__ bias,
                                              void* __restrict__ Out) {
    static_assert(NOUT % 16 == 0, "");
    constexpr int NF = NOUT / 16;
    __shared__ __bf16 sA[64 * 200];      // padded stride 200 (2-way bank max)
    __shared__ __bf16 sB[NOUT * 40];     // padded stride 40
    const int tid = threadIdx.x;
    const long rowbase = (long)blockIdx.x * 64;
    if (ABF16) {
        const __bf16* A = (const __bf16*)Asrc + rowbase * CDIM;
        for (int i = tid; i < 64 * CDIM; i += 256)
            sA[(i / CDIM) * 200 + (i % CDIM)] = A[i];
    } else {
        const float* A = (const float*)Asrc + rowbase * CDIM;
        for (int i = tid; i < 64 * CDIM; i += 256)
            sA[(i / CDIM) * 200 + (i % CDIM)] = (__bf16)A[i];
    }
    const int lane = tid & 63, wv = tid >> 6;
    const int l16 = lane & 15, lq = lane >> 4;
    f32x4 acc[NF];
#pragma unroll
    for (int nf = 0; nf < NF; ++nf) acc[nf] = (f32x4){0.f, 0.f, 0.f, 0.f};
    const __bf16* aptr = sA + (wv * 16 + l16) * 200 + lq * 8;
    for (int kc = 0; kc < 6; ++kc) {
        __syncthreads();
        for (int i = tid; i < NOUT * 32; i += 256) {
            int r = i >> 5, kk = i & 31;
            sB[r * 40 + kk] = Wb[r * CDIM + kc * 32 + kk];
        }
        __syncthreads();
        bf16x8 af = *(const bf16x8*)(aptr + kc * 32);
#pragma unroll
        for (int nf = 0; nf < NF; ++nf) {
            bf16x8 bfv = *(const bf16x8*)(sB + (nf * 16 + l16) * 40 + lq * 8);
            acc[nf] = __builtin_amdgcn_mfma_f32_16x16x32_bf16(af, bfv, acc[nf], 0, 0, 0);
        }
    }
    const long orow0 = rowbase + wv * 16 + lq * 4;
#pragma unroll
    for (int nf = 0; nf < NF; ++nf) {
        int col = nf * 16 + l16;
        float bv = BIAS ? bias[col] : 0.f;
#pragma unroll
        for (int j = 0; j < 4; ++j) {
            float val = acc[nf][j] + bv;
            long idx = (orow0 + j) * NOUT + col;
            if (OUTBF16) ((__bf16*)Out)[idx] = (__bf16)val;
            else ((float*)Out)[idx] = val;
        }
    }
}

// ---------------- K5: CPE depthwise 3x3 over v image, vp = v + cpe ----------------
__global__ void k_cpe(const __bf16* __restrict__ v, const float* __restrict__ cw,
                      const float* __restrict__ cb, __bf16* __restrict__ vp) {
    int yrow = blockIdx.x, b = blockIdx.y;
    int tid = threadIdx.x;            // 0..191
    int cr = tid % 96, xh = tid / 96;
    float wreg[9];
#pragma unroll
    for (int i = 0; i < 9; ++i) wreg[i] = cw[cr * 9 + i];
    float bias = cb[cr];
    const __bf16* vb = v + (long)b * NTOK * CRDIM + cr;
    __bf16* vpb = vp + (long)b * NTOK * CRDIM + cr;
    for (int xc = 0; xc < 64; ++xc) {
        int x = xc * 2 + xh;
        int n = yrow * WIMG + x;
        float acc = (float)vb[(long)n * CRDIM] + bias;
#pragma unroll
        for (int ki = 0; ki < 3; ++ki) {
            int yy = yrow + ki - 1;
            if (yy < 0 || yy >= HIMG) continue;
#pragma unroll
            for (int kj = 0; kj < 3; ++kj) {
                int xx = x + kj - 1;
                if (xx < 0 || xx >= WIMG) continue;
                acc += wreg[ki * 3 + kj] * (float)vb[(long)(yy * WIMG + xx) * CRDIM];
            }
        }
        vpb[(long)n * CRDIM] = (__bf16)acc;
    }
}

// ---------------- K5b: O[b, d*8*N + h*N + n] = sum_e attn[b,h,d,e]*vp[b,n,h*12+e] ----------------
// O stored flat in the torch-reshape scramble order -> proj becomes a plain GEMM.
__global__ __launch_bounds__(256) void k_av(const __bf16* __restrict__ vp,
                                            const float* __restrict__ attn,
                                            __bf16* __restrict__ O) {
    __shared__ float sAttn[NHEAD * HDIM * CRHD];   // 2304
    int chunk = blockIdx.x, b = blockIdx.y;
    int tid = threadIdx.x;
    for (int i = tid; i < NHEAD * HDIM * CRHD; i += 256)
        sAttn[i] = attn[b * NHEAD * HDIM * CRHD + i];
    __syncthreads();
    int n = chunk * 256 + tid;
    const __bf16* vrow = vp + ((long)b * NTOK + n) * CRDIM;
    __bf16* ob = O + (long)b * (HDIM * NHEAD * NTOK);
    for (int h = 0; h < NHEAD; ++h) {
        bf16x4 v0 = *(const bf16x4*)(vrow + h * CRHD);
        bf16x4 v1 = *(const bf16x4*)(vrow + h * CRHD + 4);
        bf16x4 v2 = *(const bf16x4*)(vrow + h * CRHD + 8);
        float pv[CRHD];
#pragma unroll
        for (int e = 0; e < 4; ++e) {
            pv[e] = (float)v0[e]; pv[4 + e] = (float)v1[e]; pv[8 + e] = (float)v2[e];
        }
        const float* ar = sAttn + h * HDIM * CRHD;
#pragma unroll
        for (int d = 0; d < HDIM; ++d) {
            float s = 0.f;
#pragma unroll
            for (int e = 0; e < CRHD; ++e) s += ar[d * CRHD + e] * pv[e];
            ob[(long)(d * NHEAD + h) * NTOK + n] = (__bf16)s;
        }
    }
}

extern "C" void kernel_launch(void* const* d_in, const int* in_sizes, int n_in,
                              void* d_out, int out_size, void* d_ws, size_t ws_size,
                              hipStream_t stream) {
    const float* x      = (const float*)d_in[0];
    // d_in[1]=H, d_in[2]=W (fixed 128, hard-coded)
    const float* red_w  = (const float*)d_in[3];
    const float* red_b  = (const float*)d_in[4];
    const float* dw_w   = (const float*)d_in[5];
    const float* dw_b   = (const float*)d_in[6];
    const float* conv_w = (const float*)d_in[7];
    const float* conv_b = (const float*)d_in[8];
    const float* ln_g   = (const float*)d_in[9];
    const float* ln_b   = (const float*)d_in[10];
    const float* q_w    = (const float*)d_in[11];
    const float* k_w    = (const float*)d_in[12];
    const float* v_w    = (const float*)d_in[13];
    const float* cpe_w  = (const float*)d_in[14];
    const float* cpe_b  = (const float*)d_in[15];
    const float* proj_w = (const float*)d_in[16];
    const float* proj_b = (const float*)d_in[17];
    float* out = (float*)d_out;

    // ---- workspace layout (O aliases y1/xr/q/k/v, all dead before k_av) ----
    char* ws = (char*)d_ws;
    __bf16* wb_v = (__bf16*)ws;                       // 18432 bf16
    __bf16* wb_p = wb_v + CRDIM * CDIM;               // 36864 bf16
    char* R = ws + 110592;
    float*  y1   = (float*)(R + 0);                   // 786432 B
    float*  xr   = (float*)(R + 786432);              // 786432 B
    float*  qb   = (float*)(R + 1572864);             // 786432 B
    float*  kb   = (float*)(R + 2359296);             // 393216 B
    __bf16* v    = (__bf16*)(R + 2752512);            // 50331648 B
    __bf16* O    = (__bf16*)(R + 0);                  // 100663296 B (aliases the above)
    float*  attn = (float*)(ws + 110592 + 100663296); // 147456 B
    __bf16* vp   = (__bf16*)(ws + 110592 + 100663296 + 147456); // 50331648 B
    // total ws needed: 151,252,992 B

    k_prep<<<216, 256, 0, stream>>>(v_w, proj_w, wb_v);
    k_reduce<<<dim3(64, 16), 192, 0, stream>>>(x, red_w, red_b, y1);
    k_dwmix<<<dim3(64, 16), 192, 0, stream>>>(y1, dw_w, dw_b, conv_w, conv_b, ln_g, ln_b, xr);
    k_qk<<<dim3(8, 16), 256, 0, stream>>>(xr, q_w, k_w, qb, kb);
    k_attn<<<dim3(8, 16), 256, 0, stream>>>(qb, kb, attn);
    k_gemm<CRDIM, false, true, false><<<4096, 256, 0, stream>>>(x, wb_v, nullptr, v);
    k_cpe<<<dim3(128, 16), 192, 0, stream>>>(v, cpe_w, cpe_b, vp);
    k_av<<<dim3(64, 16), 256, 0, stream>>>(vp, attn, O);
    k_gemm<CDIM, true, false, true><<<4096, 256, 0, stream>>>(O, wb_p, proj_b, out);
}

// Round 3
// 697.981 us; speedup vs baseline: 1.2333x; 1.2333x over previous
//
#include <hip/hip_runtime.h>
#include <hip/hip_bf16.h>
#include <math.h>

#define NB 16
#define HIMG 128
#define WIMG 128
#define NTOK 16384
#define CDIM 192
#define CRDIM 96
#define NHEAD 8
#define HDIM 24
#define CRHD 12
#define MRED 64
#define SCALE_QK 0.28867513459481287f

typedef __bf16 bf16x8 __attribute__((ext_vector_type(8)));
typedef __bf16 bf16x4 __attribute__((ext_vector_type(4)));
typedef float f32x4 __attribute__((ext_vector_type(4)));

// ---------------- prep: convert v_w / proj_w to bf16 ----------------
__global__ void k_prep(const float* __restrict__ vw, const float* __restrict__ pw,
                       __bf16* __restrict__ wb) {
    int i = blockIdx.x * 256 + threadIdx.x;
    if (i < CRDIM * CDIM) wb[i] = (__bf16)vw[i];
    else if (i < CRDIM * CDIM + CDIM * CDIM) wb[i] = (__bf16)pw[i - CRDIM * CDIM];
}

// ---------------- K1: two stride-4 dw convs folded into effective 16x16 stride-16 ----------------
// thread = (c4: group of 4 channels, m: output pixel, b). float4 loads.
__global__ __launch_bounds__(256) void k_reduce(const float* __restrict__ x,
                                                const float* __restrict__ rw,
                                                const float* __restrict__ rb,
                                                float* __restrict__ y1) {
    int idx = blockIdx.x * 256 + threadIdx.x;   // 48*64*16 = 49152
    int c4 = idx % 48;
    int t  = idx / 48;
    int m  = t & 63;
    int b  = t >> 6;
    float w[16][4];
#pragma unroll
    for (int e = 0; e < 4; ++e)
#pragma unroll
        for (int i = 0; i < 16; ++i) w[i][e] = rw[(c4 * 4 + e) * 16 + i];
    int py = m >> 3, px = m & 7;
    const float4* xb = (const float4*)(x + (long)b * NTOK * CDIM) + c4;
    float acc[4] = {0.f, 0.f, 0.f, 0.f};
    for (int a = 0; a < 16; ++a) {
        const float4* xrow = xb + (long)((py * 16 + a) * WIMG + px * 16) * 48;
#pragma unroll
        for (int bb = 0; bb < 16; ++bb) {
            float4 vv = xrow[(long)bb * 48];
            int i1 = ((a >> 2) << 2) + (bb >> 2);
            int i2 = ((a & 3) << 2) + (bb & 3);
            acc[0] += w[i1][0] * w[i2][0] * vv.x;
            acc[1] += w[i1][1] * w[i2][1] * vv.y;
            acc[2] += w[i1][2] * w[i2][2] * vv.z;
            acc[3] += w[i1][3] * w[i2][3] * vv.w;
        }
    }
    float4 outv;
#pragma unroll
    for (int e = 0; e < 4; ++e) {
        float S = 0.f;
#pragma unroll
        for (int i = 0; i < 16; ++i) S += w[i][e];
        acc[e] += rb[c4 * 4 + e] * (S + 1.f);
        ((float*)&outv)[e] = acc[e];
    }
    ((float4*)(y1 + (long)(b * MRED + m) * CDIM))[c4] = outv;
}

// ---------------- K2: dw3x3 + 1x1 mix + LN + exact GELU ----------------
__global__ void k_dwmix(const float* __restrict__ y1, const float* __restrict__ dww,
                        const float* __restrict__ dwb, const float* __restrict__ cw,
                        const float* __restrict__ cb, const float* __restrict__ lg,
                        const float* __restrict__ lb, float* __restrict__ xr) {
    __shared__ float sT[CDIM];
    __shared__ float sU[CDIM];
    int m = blockIdx.x, b = blockIdx.y, c = threadIdx.x;
    int py = m >> 3, px = m & 7;
    float t = dwb[c];
#pragma unroll
    for (int ki = 0; ki < 3; ++ki)
#pragma unroll
        for (int kj = 0; kj < 3; ++kj) {
            int yy = py + ki - 1, xx = px + kj - 1;
            if (yy >= 0 && yy < 8 && xx >= 0 && xx < 8)
                t += dww[c * 9 + ki * 3 + kj] * y1[(b * MRED + yy * 8 + xx) * CDIM + c];
        }
    sT[c] = t;
    __syncthreads();
    float u = cb[c];
    for (int cc = 0; cc < CDIM; ++cc) u += cw[c * CDIM + cc] * sT[cc];
    sU[c] = u;
    __syncthreads();
    float s = 0.f, s2 = 0.f;
    for (int cc = 0; cc < CDIM; ++cc) { float vv = sU[cc]; s += vv; s2 += vv * vv; }
    float mu = s * (1.f / CDIM);
    float var = fmaxf(s2 * (1.f / CDIM) - mu * mu, 0.f);
    float xh = (u - mu) * rsqrtf(var + 1e-5f);
    float g = xh * lg[c] + lb[c];
    float ge = 0.5f * g * (1.f + erff(g * 0.70710678118654752440f));
    xr[(b * MRED + m) * CDIM + c] = ge;
}

// ---------------- K3a: q = xr@q_w^T, k = xr@k_w^T ----------------
__global__ void k_qk(const float* __restrict__ xr, const float* __restrict__ qw,
                     const float* __restrict__ kw, float* __restrict__ q,
                     float* __restrict__ k) {
    __shared__ float sx[8 * 193];
    int mg = blockIdx.x;   // 0..7 (group of 8 reduced tokens)
    int b = blockIdx.y;
    int tid = threadIdx.x;
    const float* src = xr + (b * MRED + mg * 8) * CDIM;
    for (int i = tid; i < 8 * CDIM; i += 256) sx[(i / CDIM) * 193 + (i % CDIM)] = src[i];
    __syncthreads();
    for (int oi = tid; oi < 1536 + 768; oi += 256) {
        if (oi < 1536) {
            int d = oi >> 3, mi = oi & 7;
            const float* wr = qw + d * CDIM;
            const float* xs = sx + mi * 193;
            float acc = 0.f;
            for (int c = 0; c < CDIM; ++c) acc += xs[c] * wr[c];
            q[(b * MRED + mg * 8 + mi) * CDIM + d] = acc;
        } else {
            int oj = oi - 1536;
            int e = oj >> 3, mi = oj & 7;
            const float* wr = kw + e * CDIM;
            const float* xs = sx + mi * 193;
            float acc = 0.f;
            for (int c = 0; c < CDIM; ++c) acc += xs[c] * wr[c];
            k[(b * MRED + mg * 8 + mi) * CRDIM + e] = acc;
        }
    }
}

// ---------------- K3b: logits over m (64) + softmax over e (12) ----------------
__global__ void k_attn(const float* __restrict__ q, const float* __restrict__ k,
                       float* __restrict__ attn) {
    __shared__ float sL[HDIM * CRHD];
    int h = blockIdx.x, b = blockIdx.y;
    int tid = threadIdx.x;
    for (int i = tid; i < HDIM * CRHD; i += 256) {
        int d = i / CRHD, e = i % CRHD;
        float acc = 0.f;
        for (int m = 0; m < MRED; ++m)
            acc += q[(b * MRED + m) * CDIM + h * HDIM + d] *
                   k[(b * MRED + m) * CRDIM + h * CRHD + e];
        sL[i] = acc * SCALE_QK;
    }
    __syncthreads();
    if (tid < HDIM) {
        float mx = -1e30f;
#pragma unroll
        for (int e = 0; e < CRHD; ++e) mx = fmaxf(mx, sL[tid * CRHD + e]);
        float ex[CRHD]; float sum = 0.f;
#pragma unroll
        for (int e = 0; e < CRHD; ++e) { ex[e] = expf(sL[tid * CRHD + e] - mx); sum += ex[e]; }
        float inv = 1.f / sum;
#pragma unroll
        for (int e = 0; e < CRHD; ++e)
            attn[((b * NHEAD + h) * HDIM + tid) * CRHD + e] = ex[e] * inv;
    }
}

// ---------------- MFMA GEMM: C[rows,NOUT] = A[rows,192] @ W[NOUT,192]^T (+bias) ----------------
// rows = 262144 total, 64-row tiles. 4 waves, each 1 M-frag x NF N-frags, K=6x32.
// sA stride 200 elems = 400 B (16B-mult, 2-way bank max); sB stride 40 elems = 80 B.
template <int NOUT, bool ABF16, bool OUTBF16, bool BIAS>
__global__ __launch_bounds__(256) void k_gemm(const void* __restrict__ Asrc,
                                              const __bf16* __restrict__ Wb,
                                              const float* __restrict__ bias,
                                              void* __restrict__ Out) {
    static_assert(NOUT % 16 == 0, "");
    constexpr int NF = NOUT / 16;
    __shared__ __bf16 sA[64 * 200];
    __shared__ __bf16 sB[NOUT * 40];
    const int tid = threadIdx.x;
    const long rowbase = (long)blockIdx.x * 64;
    if (ABF16) {
        const __bf16* A = (const __bf16*)Asrc + rowbase * CDIM;
        for (int i = tid; i < 64 * 24; i += 256) {      // 24 x bf16x8 per row
            int r = i / 24, c8 = i % 24;
            bf16x8 vv = *(const bf16x8*)(A + (long)r * CDIM + c8 * 8);
            *(bf16x8*)(sA + r * 200 + c8 * 8) = vv;     // byte r*400+c8*16: 16B aligned
        }
    } else {
        const float* A = (const float*)Asrc + rowbase * CDIM;
        for (int i = tid; i < 64 * 24; i += 256) {
            int r = i / 24, c8 = i % 24;
            const float4* src = (const float4*)(A + (long)r * CDIM + c8 * 8);
            float4 lo = src[0], hi = src[1];
            bf16x8 vv;
            vv[0] = (__bf16)lo.x; vv[1] = (__bf16)lo.y; vv[2] = (__bf16)lo.z; vv[3] = (__bf16)lo.w;
            vv[4] = (__bf16)hi.x; vv[5] = (__bf16)hi.y; vv[6] = (__bf16)hi.z; vv[7] = (__bf16)hi.w;
            *(bf16x8*)(sA + r * 200 + c8 * 8) = vv;
        }
    }
    const int lane = tid & 63, wv = tid >> 6;
    const int l16 = lane & 15, lq = lane >> 4;
    f32x4 acc[NF];
#pragma unroll
    for (int nf = 0; nf < NF; ++nf) acc[nf] = (f32x4){0.f, 0.f, 0.f, 0.f};
    const __bf16* aptr = sA + (wv * 16 + l16) * 200 + lq * 8;
    for (int kc = 0; kc < 6; ++kc) {
        __syncthreads();
        for (int i = tid; i < NOUT * 4; i += 256) {     // 4 x bf16x8 per W row
            int r = i >> 2, c8 = i & 3;
            bf16x8 vv = *(const bf16x8*)(Wb + (long)r * CDIM + kc * 32 + c8 * 8);
            *(bf16x8*)(sB + r * 40 + c8 * 8) = vv;      // byte r*80+c8*16: 16B aligned
        }
        __syncthreads();
        bf16x8 af = *(const bf16x8*)(aptr + kc * 32);
#pragma unroll
        for (int nf = 0; nf < NF; ++nf) {
            bf16x8 bfv = *(const bf16x8*)(sB + (nf * 16 + l16) * 40 + lq * 8);
            acc[nf] = __builtin_amdgcn_mfma_f32_16x16x32_bf16(af, bfv, acc[nf], 0, 0, 0);
        }
    }
    const long orow0 = rowbase + wv * 16 + lq * 4;
#pragma unroll
    for (int nf = 0; nf < NF; ++nf) {
        int col = nf * 16 + l16;
        float bv = BIAS ? bias[col] : 0.f;
#pragma unroll
        for (int j = 0; j < 4; ++j) {
            float val = acc[nf][j] + bv;
            long idx = (orow0 + j) * NOUT + col;
            if (OUTBF16) ((__bf16*)Out)[idx] = (__bf16)val;
            else ((float*)Out)[idx] = val;
        }
    }
}

// ---------------- K5: CPE depthwise 3x3 over v image, vp = v + cpe ----------------
// thread = (g: 8-ch group, x, 8-row strip, b); bf16x8 tap loads, weights in regs.
__global__ __launch_bounds__(256) void k_cpe(const __bf16* __restrict__ v,
                                             const float* __restrict__ cw,
                                             const float* __restrict__ cb,
                                             __bf16* __restrict__ vp) {
    int idx = blockIdx.x * 256 + threadIdx.x;   // 12*128*16*16 = 393216
    int g  = idx % 12;
    int t  = idx / 12;
    int x  = t & 127;
    int sb = t >> 7;
    int strip = sb & 15;
    int b  = sb >> 4;
    float w[9][8];
    float bias[8];
#pragma unroll
    for (int e = 0; e < 8; ++e) {
        bias[e] = cb[g * 8 + e];
#pragma unroll
        for (int tp = 0; tp < 9; ++tp) w[tp][e] = cw[(g * 8 + e) * 9 + tp];
    }
    const __bf16* vb = v + (long)b * NTOK * CRDIM + g * 8;
    __bf16* vpb = vp + (long)b * NTOK * CRDIM + g * 8;
    for (int yi = 0; yi < 8; ++yi) {
        int y = strip * 8 + yi;
        bf16x8 cv = *(const bf16x8*)(vb + (long)(y * WIMG + x) * CRDIM);
        float acc[8];
#pragma unroll
        for (int e = 0; e < 8; ++e) acc[e] = (float)cv[e] + bias[e];
#pragma unroll
        for (int ky = 0; ky < 3; ++ky) {
            int yy = y + ky - 1;
            if (yy < 0 || yy >= HIMG) continue;
#pragma unroll
            for (int kx = 0; kx < 3; ++kx) {
                int xx = x + kx - 1;
                if (xx < 0 || xx >= WIMG) continue;
                bf16x8 tv = (ky == 1 && kx == 1) ? cv
                          : *(const bf16x8*)(vb + (long)(yy * WIMG + xx) * CRDIM);
#pragma unroll
                for (int e = 0; e < 8; ++e) acc[e] += w[ky * 3 + kx][e] * (float)tv[e];
            }
        }
        bf16x8 ov;
#pragma unroll
        for (int e = 0; e < 8; ++e) ov[e] = (__bf16)acc[e];
        *(bf16x8*)(vpb + (long)(y * WIMG + x) * CRDIM) = ov;
    }
}

// ---------------- K5b: O[b, d*8*N + h*N + n] = sum_e attn[b,h,d,e]*vp[b,n,h*12+e] ----------------
// O stored flat in the torch-reshape scramble order -> proj becomes a plain GEMM.
__global__ __launch_bounds__(256) void k_av(const __bf16* __restrict__ vp,
                                            const float* __restrict__ attn,
                                            __bf16* __restrict__ O) {
    __shared__ float sAttn[NHEAD * HDIM * CRHD];   // 2304
    int chunk = blockIdx.x, b = blockIdx.y;
    int tid = threadIdx.x;
    for (int i = tid; i < NHEAD * HDIM * CRHD; i += 256)
        sAttn[i] = attn[b * NHEAD * HDIM * CRHD + i];
    __syncthreads();
    int n = chunk * 256 + tid;
    const __bf16* vrow = vp + ((long)b * NTOK + n) * CRDIM;
    __bf16* ob = O + (long)b * (HDIM * NHEAD * NTOK);
    for (int h = 0; h < NHEAD; ++h) {
        bf16x4 v0 = *(const bf16x4*)(vrow + h * CRHD);
        bf16x4 v1 = *(const bf16x4*)(vrow + h * CRHD + 4);
        bf16x4 v2 = *(const bf16x4*)(vrow + h * CRHD + 8);
        float pv[CRHD];
#pragma unroll
        for (int e = 0; e < 4; ++e) {
            pv[e] = (float)v0[e]; pv[4 + e] = (float)v1[e]; pv[8 + e] = (float)v2[e];
        }
        const float* ar = sAttn + h * HDIM * CRHD;
#pragma unroll
        for (int d = 0; d < HDIM; ++d) {
            float s = 0.f;
#pragma unroll
            for (int e = 0; e < CRHD; ++e) s += ar[d * CRHD + e] * pv[e];
            ob[(long)(d * NHEAD + h) * NTOK + n] = (__bf16)s;
        }
    }
}

extern "C" void kernel_launch(void* const* d_in, const int* in_sizes, int n_in,
                              void* d_out, int out_size, void* d_ws, size_t ws_size,
                              hipStream_t stream) {
    const float* x      = (const float*)d_in[0];
    // d_in[1]=H, d_in[2]=W (fixed 128, hard-coded)
    const float* red_w  = (const float*)d_in[3];
    const float* red_b  = (const float*)d_in[4];
    const float* dw_w   = (const float*)d_in[5];
    const float* dw_b   = (const float*)d_in[6];
    const float* conv_w = (const float*)d_in[7];
    const float* conv_b = (const float*)d_in[8];
    const float* ln_g   = (const float*)d_in[9];
    const float* ln_b   = (const float*)d_in[10];
    const float* q_w    = (const float*)d_in[11];
    const float* k_w    = (const float*)d_in[12];
    const float* v_w    = (const float*)d_in[13];
    const float* cpe_w  = (const float*)d_in[14];
    const float* cpe_b  = (const float*)d_in[15];
    const float* proj_w = (const float*)d_in[16];
    const float* proj_b = (const float*)d_in[17];
    float* out = (float*)d_out;

    // ---- workspace layout (O aliases y1/xr/q/k/v, all dead before k_av) ----
    char* ws = (char*)d_ws;
    __bf16* wb_v = (__bf16*)ws;                       // 18432 bf16
    __bf16* wb_p = wb_v + CRDIM * CDIM;               // 36864 bf16
    char* R = ws + 110592;
    float*  y1   = (float*)(R + 0);                   // 786432 B
    float*  xr   = (float*)(R + 786432);              // 786432 B
    float*  qb   = (float*)(R + 1572864);             // 786432 B
    float*  kb   = (float*)(R + 2359296);             // 393216 B
    __bf16* v    = (__bf16*)(R + 2752512);            // 50331648 B
    __bf16* O    = (__bf16*)(R + 0);                  // 100663296 B (aliases the above)
    float*  attn = (float*)(ws + 110592 + 100663296); // 147456 B
    __bf16* vp   = (__bf16*)(ws + 110592 + 100663296 + 147456); // 50331648 B
    // total ws needed: 151,252,992 B

    k_prep<<<216, 256, 0, stream>>>(v_w, proj_w, wb_v);
    k_reduce<<<192, 256, 0, stream>>>(x, red_w, red_b, y1);
    k_dwmix<<<dim3(64, 16), 192, 0, stream>>>(y1, dw_w, dw_b, conv_w, conv_b, ln_g, ln_b, xr);
    k_qk<<<dim3(8, 16), 256, 0, stream>>>(xr, q_w, k_w, qb, kb);
    k_attn<<<dim3(8, 16), 256, 0, stream>>>(qb, kb, attn);
    k_gemm<CRDIM, false, true, false><<<4096, 256, 0, stream>>>(x, wb_v, nullptr, v);
    k_cpe<<<1536, 256, 0, stream>>>(v, cpe_w, cpe_b, vp);
    k_av<<<dim3(64, 16), 256, 0, stream>>>(vp, attn, O);
    k_gemm<CDIM, true, false, true><<<4096, 256, 0, stream>>>(O, wb_p, proj_b, out);
}

// Round 4
// 693.210 us; speedup vs baseline: 1.2418x; 1.0069x over previous
//
#include <hip/hip_runtime.h>
#include <hip/hip_bf16.h>
#include <math.h>

#define NB 16
#define HIMG 128
#define WIMG 128
#define NTOK 16384
#define CDIM 192
#define CRDIM 96
#define NHEAD 8
#define HDIM 24
#define CRHD 12
#define MRED 64
#define SCALE_QK 0.28867513459481287f

typedef __bf16 bf16x8 __attribute__((ext_vector_type(8)));
typedef __bf16 bf16x4 __attribute__((ext_vector_type(4)));
typedef __bf16 bf16x2 __attribute__((ext_vector_type(2)));
typedef float f32x4 __attribute__((ext_vector_type(4)));

// ---------------- prep: convert v_w / proj_w to bf16 ----------------
__global__ void k_prep(const float* __restrict__ vw, const float* __restrict__ pw,
                       __bf16* __restrict__ wb) {
    int i = blockIdx.x * 256 + threadIdx.x;
    if (i < CRDIM * CDIM) wb[i] = (__bf16)vw[i];
    else if (i < CRDIM * CDIM + CDIM * CDIM) wb[i] = (__bf16)pw[i - CRDIM * CDIM];
}

// ---------------- K1: folded 16x16 stride-16 dw conv; a-rows split 4-way ----------------
// block = one (b,m) output pixel, 192 threads = 48 c4-groups x 4 a4-slices.
__global__ __launch_bounds__(192) void k_reduce(const float* __restrict__ x,
                                                const float* __restrict__ rw,
                                                const float* __restrict__ rb,
                                                float* __restrict__ y1) {
    __shared__ float4 sRed[4][48];
    int tid = threadIdx.x;
    int c4 = tid % 48, a4 = tid / 48;
    int m = blockIdx.x & 63, b = blockIdx.x >> 6;
    float w[16][4];
#pragma unroll
    for (int e = 0; e < 4; ++e)
#pragma unroll
        for (int i = 0; i < 16; ++i) w[i][e] = rw[(c4 * 4 + e) * 16 + i];
    int py = m >> 3, px = m & 7;
    const float4* xb = (const float4*)(x + (long)b * NTOK * CDIM) + c4;
    float acc[4] = {0.f, 0.f, 0.f, 0.f};
#pragma unroll
    for (int ai = 0; ai < 4; ++ai) {
        int a = a4 * 4 + ai;
        const float4* xrow = xb + (long)((py * 16 + a) * WIMG + px * 16) * 48;
#pragma unroll
        for (int bb = 0; bb < 16; ++bb) {
            float4 vv = xrow[(long)bb * 48];
            int i1 = ((a >> 2) << 2) + (bb >> 2);
            int i2 = ((a & 3) << 2) + (bb & 3);
            acc[0] += w[i1][0] * w[i2][0] * vv.x;
            acc[1] += w[i1][1] * w[i2][1] * vv.y;
            acc[2] += w[i1][2] * w[i2][2] * vv.z;
            acc[3] += w[i1][3] * w[i2][3] * vv.w;
        }
    }
    sRed[a4][c4] = make_float4(acc[0], acc[1], acc[2], acc[3]);
    __syncthreads();
    if (a4 == 0) {
        float4 t0 = sRed[0][c4], t1 = sRed[1][c4], t2 = sRed[2][c4], t3 = sRed[3][c4];
        float4 outv;
        float r[4] = {t0.x + t1.x + t2.x + t3.x, t0.y + t1.y + t2.y + t3.y,
                      t0.z + t1.z + t2.z + t3.z, t0.w + t1.w + t2.w + t3.w};
#pragma unroll
        for (int e = 0; e < 4; ++e) {
            float S = 0.f;
#pragma unroll
            for (int i = 0; i < 16; ++i) S += w[i][e];
            ((float*)&outv)[e] = r[e] + rb[c4 * 4 + e] * (S + 1.f);
        }
        ((float4*)(y1 + (long)(b * MRED + m) * CDIM))[c4] = outv;
    }
}

// ---------------- K2: dw3x3 + 1x1 mix + LN + exact GELU ----------------
__global__ void k_dwmix(const float* __restrict__ y1, const float* __restrict__ dww,
                        const float* __restrict__ dwb, const float* __restrict__ cw,
                        const float* __restrict__ cb, const float* __restrict__ lg,
                        const float* __restrict__ lb, float* __restrict__ xr) {
    __shared__ float sT[CDIM];
    __shared__ float sU[CDIM];
    int m = blockIdx.x, b = blockIdx.y, c = threadIdx.x;
    int py = m >> 3, px = m & 7;
    float t = dwb[c];
#pragma unroll
    for (int ki = 0; ki < 3; ++ki)
#pragma unroll
        for (int kj = 0; kj < 3; ++kj) {
            int yy = py + ki - 1, xx = px + kj - 1;
            if (yy >= 0 && yy < 8 && xx >= 0 && xx < 8)
                t += dww[c * 9 + ki * 3 + kj] * y1[(b * MRED + yy * 8 + xx) * CDIM + c];
        }
    sT[c] = t;
    __syncthreads();
    float u = cb[c];
    for (int cc = 0; cc < CDIM; ++cc) u += cw[c * CDIM + cc] * sT[cc];
    sU[c] = u;
    __syncthreads();
    float s = 0.f, s2 = 0.f;
    for (int cc = 0; cc < CDIM; ++cc) { float vv = sU[cc]; s += vv; s2 += vv * vv; }
    float mu = s * (1.f / CDIM);
    float var = fmaxf(s2 * (1.f / CDIM) - mu * mu, 0.f);
    float xh = (u - mu) * rsqrtf(var + 1e-5f);
    float g = xh * lg[c] + lb[c];
    float ge = 0.5f * g * (1.f + erff(g * 0.70710678118654752440f));
    xr[(b * MRED + m) * CDIM + c] = ge;
}

// ---------------- K3: fused q/k projection + logits + softmax per (h,b) ----------------
__global__ __launch_bounds__(256) void k_qkattn(const float* __restrict__ xr,
                                                const float* __restrict__ qw,
                                                const float* __restrict__ kw,
                                                float* __restrict__ attn) {
    __shared__ float sX[64 * 193];   // 49.4 KB
    __shared__ float sQK[36 * 65];   // 9.4 KB  (24 q-cols then 12 k-cols)
    __shared__ float sL[HDIM * CRHD];
    int h = blockIdx.x, b = blockIdx.y, tid = threadIdx.x;
    const float* src = xr + (long)b * MRED * CDIM;
    for (int i = tid; i < MRED * CDIM; i += 256) sX[(i / CDIM) * 193 + (i % CDIM)] = src[i];
    __syncthreads();
    for (int oi = tid; oi < 36 * 64; oi += 256) {
        int col = oi >> 6, tok = oi & 63;
        const float* wr = (col < 24) ? (qw + (long)(h * HDIM + col) * CDIM)
                                     : (kw + (long)(h * CRHD + (col - 24)) * CDIM);
        const float* xs = sX + tok * 193;
        float acc = 0.f;
        for (int c = 0; c < CDIM; ++c) acc += xs[c] * wr[c];
        sQK[col * 65 + tok] = acc;
    }
    __syncthreads();
    for (int oi = tid; oi < HDIM * CRHD; oi += 256) {
        int d = oi / CRHD, e = oi % CRHD;
        float acc = 0.f;
        for (int t = 0; t < 64; ++t) acc += sQK[d * 65 + t] * sQK[(24 + e) * 65 + t];
        sL[oi] = acc * SCALE_QK;
    }
    __syncthreads();
    if (tid < HDIM) {
        float mx = -1e30f;
#pragma unroll
        for (int e = 0; e < CRHD; ++e) mx = fmaxf(mx, sL[tid * CRHD + e]);
        float ex[CRHD]; float sum = 0.f;
#pragma unroll
        for (int e = 0; e < CRHD; ++e) { ex[e] = expf(sL[tid * CRHD + e] - mx); sum += ex[e]; }
        float inv = 1.f / sum;
#pragma unroll
        for (int e = 0; e < CRHD; ++e)
            attn[((b * NHEAD + h) * HDIM + tid) * CRHD + e] = ex[e] * inv;
    }
}

// ---------------- MFMA GEMM: C[rows,NOUT] = A[rows,192] @ W[NOUT,192]^T (+bias) ----------------
// 64-row tiles; NSPLIT col-halves per tile. Whole W-slice preloaded once -> 1 barrier.
// Wave owns 2 m-frags x 3 n-frags (30 ds_read_b128, 36 MFMA per wave).
template <int NOUT, int NSPLIT, bool ABF16, bool OUTBF16, bool BIAS>
__global__ __launch_bounds__(256) void k_gemm(const void* __restrict__ Asrc,
                                              const __bf16* __restrict__ Wb,
                                              const float* __restrict__ bias,
                                              void* __restrict__ Out) {
    constexpr int NC = NOUT / NSPLIT;    // cols per block (96)
    constexpr int NFW = 3;               // n-frags per wave
    __shared__ __bf16 sA[64 * 200];      // 25.6 KB
    __shared__ __bf16 sB[NC * 200];      // 38.4 KB
    const int tid = threadIdx.x;
    const int nh = (NSPLIT > 1) ? (int)(blockIdx.x % NSPLIT) : 0;
    const long tile = (NSPLIT > 1) ? (blockIdx.x / NSPLIT) : blockIdx.x;
    const long rowbase = tile * 64;
    if (ABF16) {
        const __bf16* A = (const __bf16*)Asrc + rowbase * CDIM;
        for (int i = tid; i < 64 * 24; i += 256) {
            int r = i / 24, c8 = i % 24;
            *(bf16x8*)(sA + r * 200 + c8 * 8) = *(const bf16x8*)(A + (long)r * CDIM + c8 * 8);
        }
    } else {
        const float* A = (const float*)Asrc + rowbase * CDIM;
        for (int i = tid; i < 64 * 24; i += 256) {
            int r = i / 24, c8 = i % 24;
            const float4* s4 = (const float4*)(A + (long)r * CDIM + c8 * 8);
            float4 lo = s4[0], hi = s4[1];
            bf16x8 vv;
            vv[0] = (__bf16)lo.x; vv[1] = (__bf16)lo.y; vv[2] = (__bf16)lo.z; vv[3] = (__bf16)lo.w;
            vv[4] = (__bf16)hi.x; vv[5] = (__bf16)hi.y; vv[6] = (__bf16)hi.z; vv[7] = (__bf16)hi.w;
            *(bf16x8*)(sA + r * 200 + c8 * 8) = vv;
        }
    }
    for (int i = tid; i < NC * 24; i += 256) {
        int r = i / 24, c8 = i % 24;
        *(bf16x8*)(sB + r * 200 + c8 * 8) =
            *(const bf16x8*)(Wb + (long)(nh * NC + r) * CDIM + c8 * 8);
    }
    __syncthreads();
    const int lane = tid & 63, wv = tid >> 6;
    const int l16 = lane & 15, lq = lane >> 4;
    const int mi0 = (wv >> 1) * 2;   // m-frag base: 0 or 2
    const int nf0 = (wv & 1) * 3;    // n-frag base: 0 or 3
    f32x4 acc[2][NFW];
#pragma unroll
    for (int mi = 0; mi < 2; ++mi)
#pragma unroll
        for (int nf = 0; nf < NFW; ++nf) acc[mi][nf] = (f32x4){0.f, 0.f, 0.f, 0.f};
    bf16x8 afr[2][6];
#pragma unroll
    for (int mi = 0; mi < 2; ++mi)
#pragma unroll
        for (int kc = 0; kc < 6; ++kc)
            afr[mi][kc] = *(const bf16x8*)(sA + ((mi0 + mi) * 16 + l16) * 200 + kc * 32 + lq * 8);
#pragma unroll
    for (int kc = 0; kc < 6; ++kc)
#pragma unroll
        for (int nf = 0; nf < NFW; ++nf) {
            bf16x8 bfv = *(const bf16x8*)(sB + ((nf0 + nf) * 16 + l16) * 200 + kc * 32 + lq * 8);
#pragma unroll
            for (int mi = 0; mi < 2; ++mi)
                acc[mi][nf] = __builtin_amdgcn_mfma_f32_16x16x32_bf16(afr[mi][kc], bfv,
                                                                      acc[mi][nf], 0, 0, 0);
        }
#pragma unroll
    for (int mi = 0; mi < 2; ++mi) {
        const long orow0 = rowbase + (mi0 + mi) * 16 + lq * 4;
#pragma unroll
        for (int nf = 0; nf < NFW; ++nf) {
            int col = nh * NC + (nf0 + nf) * 16 + l16;
            float bv = BIAS ? bias[col] : 0.f;
#pragma unroll
            for (int j = 0; j < 4; ++j) {
                float val = acc[mi][nf][j] + bv;
                long idx = (orow0 + j) * NOUT + col;
                if (OUTBF16) ((__bf16*)Out)[idx] = (__bf16)val;
                else ((float*)Out)[idx] = val;
            }
        }
    }
}

// ---------------- K5: fused CPE(3x3 dw on v) + attn@v^T, O in scramble order ----------------
// thread = 2 adjacent tokens (n0, n0+1); per head h computes vp[12] on the fly.
__global__ __launch_bounds__(256) void k_avcpe(const __bf16* __restrict__ v,
                                               const float* __restrict__ attn,
                                               const float* __restrict__ cw,
                                               const float* __restrict__ cb,
                                               __bf16* __restrict__ O) {
    __shared__ float sA2[NHEAD * HDIM * CRHD];  // 2304
    __shared__ float sW[CRDIM * 9];             // 864
    __shared__ float sB2[CRDIM];                // 96
    int chunk = blockIdx.x, b = blockIdx.y, tid = threadIdx.x;
    for (int i = tid; i < NHEAD * HDIM * CRHD; i += 256)
        sA2[i] = attn[b * NHEAD * HDIM * CRHD + i];
    for (int i = tid; i < CRDIM * 9; i += 256) sW[i] = cw[i];
    if (tid < CRDIM) sB2[tid] = cb[tid];
    __syncthreads();
    int n0 = (chunk * 256 + tid) * 2;
    int y = n0 >> 7, x = n0 & 127;
    bool xm = (x > 0), xp = (x + 2 < WIMG);
    const __bf16* vb = v + (long)b * NTOK * CRDIM;
    __bf16* ob = O + (long)b * (CDIM * NTOK);
#pragma unroll
    for (int h = 0; h < NHEAD; ++h) {
        float vp0[CRHD], vp1[CRHD];
#pragma unroll
        for (int e = 0; e < CRHD; ++e) { vp0[e] = sB2[h * CRHD + e]; vp1[e] = vp0[e]; }
#pragma unroll
        for (int rr = 0; rr < 3; ++rr) {
            int ry = y + rr - 1;
            if (ry < 0 || ry >= HIMG) continue;   // wave-uniform
            const __bf16* rowp = vb + ((long)ry * WIMG) * CRDIM + h * CRHD;
#pragma unroll
            for (int cc = 0; cc < 4; ++cc) {
                int cx = x + cc - 1;
                bool valid = (cc > 0 || xm) && (cc < 3 || xp);
                float tv[CRHD];
                if (valid) {
                    const __bf16* p = rowp + (long)cx * CRDIM;
                    bf16x4 t0 = *(const bf16x4*)(p);
                    bf16x4 t1 = *(const bf16x4*)(p + 4);
                    bf16x4 t2 = *(const bf16x4*)(p + 8);
#pragma unroll
                    for (int e = 0; e < 4; ++e) {
                        tv[e] = (float)t0[e]; tv[4 + e] = (float)t1[e]; tv[8 + e] = (float)t2[e];
                    }
                } else {
#pragma unroll
                    for (int e = 0; e < CRHD; ++e) tv[e] = 0.f;
                }
                if (cc < 3) {
#pragma unroll
                    for (int e = 0; e < CRHD; ++e)
                        vp0[e] += sW[(h * CRHD + e) * 9 + rr * 3 + cc] * tv[e];
                    if (rr == 1 && cc == 1)
#pragma unroll
                        for (int e = 0; e < CRHD; ++e) vp0[e] += tv[e];   // identity (v itself)
                }
                if (cc > 0) {
#pragma unroll
                    for (int e = 0; e < CRHD; ++e)
                        vp1[e] += sW[(h * CRHD + e) * 9 + rr * 3 + cc - 1] * tv[e];
                    if (rr == 1 && cc == 2)
#pragma unroll
                        for (int e = 0; e < CRHD; ++e) vp1[e] += tv[e];
                }
            }
        }
        const float* ar = sA2 + h * HDIM * CRHD;
#pragma unroll
        for (int d = 0; d < HDIM; ++d) {
            float s0 = 0.f, s1 = 0.f;
#pragma unroll
            for (int e = 0; e < CRHD; ++e) {
                float a = ar[d * CRHD + e];
                s0 += a * vp0[e]; s1 += a * vp1[e];
            }
            bf16x2 o2; o2[0] = (__bf16)s0; o2[1] = (__bf16)s1;
            *(bf16x2*)(ob + (long)(d * NHEAD + h) * NTOK + n0) = o2;
        }
    }
}

extern "C" void kernel_launch(void* const* d_in, const int* in_sizes, int n_in,
                              void* d_out, int out_size, void* d_ws, size_t ws_size,
                              hipStream_t stream) {
    const float* x      = (const float*)d_in[0];
    const float* red_w  = (const float*)d_in[3];
    const float* red_b  = (const float*)d_in[4];
    const float* dw_w   = (const float*)d_in[5];
    const float* dw_b   = (const float*)d_in[6];
    const float* conv_w = (const float*)d_in[7];
    const float* conv_b = (const float*)d_in[8];
    const float* ln_g   = (const float*)d_in[9];
    const float* ln_b   = (const float*)d_in[10];
    const float* q_w    = (const float*)d_in[11];
    const float* k_w    = (const float*)d_in[12];
    const float* v_w    = (const float*)d_in[13];
    const float* cpe_w  = (const float*)d_in[14];
    const float* cpe_b  = (const float*)d_in[15];
    const float* proj_w = (const float*)d_in[16];
    const float* proj_b = (const float*)d_in[17];
    float* out = (float*)d_out;

    // ---- workspace (no aliasing; ~146 MB) ----
    char* ws = (char*)d_ws;
    __bf16* wb_v = (__bf16*)ws;                       // 36864 B
    __bf16* wb_p = (__bf16*)(ws + 36864);             // 73728 B
    float*  y1   = (float*)(ws + 110592);             // 786432 B
    float*  xr   = (float*)(ws + 897024);             // 786432 B
    float*  attn = (float*)(ws + 1683456);            // 147456 B
    __bf16* v    = (__bf16*)(ws + 1830912);           // 50331648 B
    __bf16* O    = (__bf16*)(ws + 52162560);          // 100663296 B

    k_prep<<<216, 256, 0, stream>>>(v_w, proj_w, wb_v);
    k_reduce<<<1024, 192, 0, stream>>>(x, red_w, red_b, y1);
    k_dwmix<<<dim3(64, 16), 192, 0, stream>>>(y1, dw_w, dw_b, conv_w, conv_b, ln_g, ln_b, xr);
    k_qkattn<<<dim3(8, 16), 256, 0, stream>>>(xr, q_w, k_w, attn);
    k_gemm<CRDIM, 1, false, true, false><<<4096, 256, 0, stream>>>(x, wb_v, nullptr, v);
    k_avcpe<<<dim3(32, 16), 256, 0, stream>>>(v, attn, cpe_w, cpe_b, O);
    k_gemm<CDIM, 2, true, false, true><<<8192, 256, 0, stream>>>(O, wb_p, proj_b, out);
}

// Round 7
// 629.741 us; speedup vs baseline: 1.3670x; 1.1008x over previous
//
#include <hip/hip_runtime.h>
#include <hip/hip_bf16.h>
#include <math.h>

#define NB 16
#define HIMG 128
#define WIMG 128
#define NTOK 16384
#define CDIM 192
#define CRDIM 96
#define NHEAD 8
#define HDIM 24
#define CRHD 12
#define MRED 64
#define SCALE_QK 0.28867513459481287f

typedef __bf16 bf16x8 __attribute__((ext_vector_type(8)));
typedef __bf16 bf16x4 __attribute__((ext_vector_type(4)));
typedef __bf16 bf16x2 __attribute__((ext_vector_type(2)));
typedef float f32x4 __attribute__((ext_vector_type(4)));

// ---------------- prep: convert v_w / proj_w to bf16 ----------------
__global__ void k_prep(const float* __restrict__ vw, const float* __restrict__ pw,
                       __bf16* __restrict__ wb) {
    int i = blockIdx.x * 256 + threadIdx.x;
    if (i < CRDIM * CDIM) wb[i] = (__bf16)vw[i];
    else if (i < CRDIM * CDIM + CDIM * CDIM) wb[i] = (__bf16)pw[i - CRDIM * CDIM];
}

// ---------------- K1: folded 16x16 stride-16 dw conv; a-rows split 4-way ----------------
__global__ __launch_bounds__(192) void k_reduce(const float* __restrict__ x,
                                                const float* __restrict__ rw,
                                                const float* __restrict__ rb,
                                                float* __restrict__ y1) {
    __shared__ float4 sRed[4][48];
    int tid = threadIdx.x;
    int c4 = tid % 48, a4 = tid / 48;
    int m = blockIdx.x & 63, b = blockIdx.x >> 6;
    float w[16][4];
#pragma unroll
    for (int e = 0; e < 4; ++e)
#pragma unroll
        for (int i = 0; i < 16; ++i) w[i][e] = rw[(c4 * 4 + e) * 16 + i];
    int py = m >> 3, px = m & 7;
    const float4* xb = (const float4*)(x + (long)b * NTOK * CDIM) + c4;
    float acc[4] = {0.f, 0.f, 0.f, 0.f};
#pragma unroll
    for (int ai = 0; ai < 4; ++ai) {
        int a = a4 * 4 + ai;
        const float4* xrow = xb + (long)((py * 16 + a) * WIMG + px * 16) * 48;
#pragma unroll
        for (int bb = 0; bb < 16; ++bb) {
            float4 vv = xrow[(long)bb * 48];
            int i1 = ((a >> 2) << 2) + (bb >> 2);
            int i2 = ((a & 3) << 2) + (bb & 3);
            acc[0] += w[i1][0] * w[i2][0] * vv.x;
            acc[1] += w[i1][1] * w[i2][1] * vv.y;
            acc[2] += w[i1][2] * w[i2][2] * vv.z;
            acc[3] += w[i1][3] * w[i2][3] * vv.w;
        }
    }
    sRed[a4][c4] = make_float4(acc[0], acc[1], acc[2], acc[3]);
    __syncthreads();
    if (a4 == 0) {
        float4 t0 = sRed[0][c4], t1 = sRed[1][c4], t2 = sRed[2][c4], t3 = sRed[3][c4];
        float4 outv;
        float r[4] = {t0.x + t1.x + t2.x + t3.x, t0.y + t1.y + t2.y + t3.y,
                      t0.z + t1.z + t2.z + t3.z, t0.w + t1.w + t2.w + t3.w};
#pragma unroll
        for (int e = 0; e < 4; ++e) {
            float S = 0.f;
#pragma unroll
            for (int i = 0; i < 16; ++i) S += w[i][e];
            ((float*)&outv)[e] = r[e] + rb[c4 * 4 + e] * (S + 1.f);
        }
        ((float4*)(y1 + (long)(b * MRED + m) * CDIM))[c4] = outv;
    }
}

// ---------------- K2: dw3x3 + 1x1 mix + LN + exact GELU ----------------
__global__ void k_dwmix(const float* __restrict__ y1, const float* __restrict__ dww,
                        const float* __restrict__ dwb, const float* __restrict__ cw,
                        const float* __restrict__ cb, const float* __restrict__ lg,
                        const float* __restrict__ lb, float* __restrict__ xr) {
    __shared__ float sT[CDIM];
    __shared__ float sU[CDIM];
    int m = blockIdx.x, b = blockIdx.y, c = threadIdx.x;
    int py = m >> 3, px = m & 7;
    float t = dwb[c];
#pragma unroll
    for (int ki = 0; ki < 3; ++ki)
#pragma unroll
        for (int kj = 0; kj < 3; ++kj) {
            int yy = py + ki - 1, xx = px + kj - 1;
            if (yy >= 0 && yy < 8 && xx >= 0 && xx < 8)
                t += dww[c * 9 + ki * 3 + kj] * y1[(b * MRED + yy * 8 + xx) * CDIM + c];
        }
    sT[c] = t;
    __syncthreads();
    float u = cb[c];
    for (int cc = 0; cc < CDIM; ++cc) u += cw[c * CDIM + cc] * sT[cc];
    sU[c] = u;
    __syncthreads();
    float s = 0.f, s2 = 0.f;
    for (int cc = 0; cc < CDIM; ++cc) { float vv = sU[cc]; s += vv; s2 += vv * vv; }
    float mu = s * (1.f / CDIM);
    float var = fmaxf(s2 * (1.f / CDIM) - mu * mu, 0.f);
    float xh = (u - mu) * rsqrtf(var + 1e-5f);
    float g = xh * lg[c] + lb[c];
    float ge = 0.5f * g * (1.f + erff(g * 0.70710678118654752440f));
    xr[(b * MRED + m) * CDIM + c] = ge;
}

// ---------------- K3: fused q/k projection + logits + softmax per (h,b) ----------------
__global__ __launch_bounds__(256) void k_qkattn(const float* __restrict__ xr,
                                                const float* __restrict__ qw,
                                                const float* __restrict__ kw,
                                                float* __restrict__ attn) {
    __shared__ float sX[64 * 193];
    __shared__ float sQK[36 * 65];
    __shared__ float sL[HDIM * CRHD];
    int h = blockIdx.x, b = blockIdx.y, tid = threadIdx.x;
    const float* src = xr + (long)b * MRED * CDIM;
    for (int i = tid; i < MRED * CDIM; i += 256) sX[(i / CDIM) * 193 + (i % CDIM)] = src[i];
    __syncthreads();
    for (int oi = tid; oi < 36 * 64; oi += 256) {
        int col = oi >> 6, tok = oi & 63;
        const float* wr = (col < 24) ? (qw + (long)(h * HDIM + col) * CDIM)
                                     : (kw + (long)(h * CRHD + (col - 24)) * CDIM);
        const float* xs = sX + tok * 193;
        float acc = 0.f;
        for (int c = 0; c < CDIM; ++c) acc += xs[c] * wr[c];
        sQK[col * 65 + tok] = acc;
    }
    __syncthreads();
    for (int oi = tid; oi < HDIM * CRHD; oi += 256) {
        int d = oi / CRHD, e = oi % CRHD;
        float acc = 0.f;
        for (int t = 0; t < 64; ++t) acc += sQK[d * 65 + t] * sQK[(24 + e) * 65 + t];
        sL[oi] = acc * SCALE_QK;
    }
    __syncthreads();
    if (tid < HDIM) {
        float mx = -1e30f;
#pragma unroll
        for (int e = 0; e < CRHD; ++e) mx = fmaxf(mx, sL[tid * CRHD + e]);
        float ex[CRHD]; float sum = 0.f;
#pragma unroll
        for (int e = 0; e < CRHD; ++e) { ex[e] = expf(sL[tid * CRHD + e] - mx); sum += ex[e]; }
        float inv = 1.f / sum;
#pragma unroll
        for (int e = 0; e < CRHD; ++e)
            attn[((b * NHEAD + h) * HDIM + tid) * CRHD + e] = ex[e] * inv;
    }
}

// ---------------- MFMA GEMM: 512 threads, 64-row x 96-col tiles, full-K preload ----------------
// 8 waves = 4 m-groups x 2 n-groups; wave = 1 m-frag x 3 n-frags; 1 barrier/block.
// 64 KB LDS -> 2 blocks/CU -> 16 waves/CU (4/SIMD).
template <int NOUT, int NSPLIT, bool ABF16, bool OUTBF16, bool BIAS>
__global__ __launch_bounds__(512) void k_gemm(const void* __restrict__ Asrc,
                                              const __bf16* __restrict__ Wb,
                                              const float* __restrict__ bias,
                                              void* __restrict__ Out) {
    constexpr int NC = NOUT / NSPLIT;    // 96 cols per block
    static_assert(NC == 96, "");
    __shared__ __bf16 sA[64 * 200];      // 25.6 KB
    __shared__ __bf16 sB[96 * 200];      // 38.4 KB
    const int tid = threadIdx.x;
    const int nh = (NSPLIT > 1) ? (int)(blockIdx.x % NSPLIT) : 0;
    const long tile = (NSPLIT > 1) ? (blockIdx.x / NSPLIT) : blockIdx.x;
    const long rowbase = tile * 64;
    if (ABF16) {
        const __bf16* A = (const __bf16*)Asrc + rowbase * CDIM;
        for (int i = tid; i < 64 * 24; i += 512) {
            int r = i / 24, c8 = i % 24;
            *(bf16x8*)(sA + r * 200 + c8 * 8) = *(const bf16x8*)(A + (long)r * CDIM + c8 * 8);
        }
    } else {
        const float* A = (const float*)Asrc + rowbase * CDIM;
        for (int i = tid; i < 64 * 24; i += 512) {
            int r = i / 24, c8 = i % 24;
            const float4* s4 = (const float4*)(A + (long)r * CDIM + c8 * 8);
            float4 lo = s4[0], hi = s4[1];
            bf16x8 vv;
            vv[0] = (__bf16)lo.x; vv[1] = (__bf16)lo.y; vv[2] = (__bf16)lo.z; vv[3] = (__bf16)lo.w;
            vv[4] = (__bf16)hi.x; vv[5] = (__bf16)hi.y; vv[6] = (__bf16)hi.z; vv[7] = (__bf16)hi.w;
            *(bf16x8*)(sA + r * 200 + c8 * 8) = vv;
        }
    }
    for (int i = tid; i < 96 * 24; i += 512) {
        int r = i / 24, c8 = i % 24;
        *(bf16x8*)(sB + r * 200 + c8 * 8) =
            *(const bf16x8*)(Wb + (long)(nh * 96 + r) * CDIM + c8 * 8);
    }
    __syncthreads();
    const int lane = tid & 63, wv = tid >> 6;      // wv 0..7
    const int l16 = lane & 15, lq = lane >> 4;
    const int mi = wv >> 1;                        // m-frag 0..3
    const int nf0 = (wv & 1) * 3;                  // n-frag base 0 or 3
    f32x4 acc[3];
#pragma unroll
    for (int nf = 0; nf < 3; ++nf) acc[nf] = (f32x4){0.f, 0.f, 0.f, 0.f};
    bf16x8 afr[6];
#pragma unroll
    for (int kc = 0; kc < 6; ++kc)
        afr[kc] = *(const bf16x8*)(sA + (mi * 16 + l16) * 200 + kc * 32 + lq * 8);
#pragma unroll
    for (int kc = 0; kc < 6; ++kc)
#pragma unroll
        for (int nf = 0; nf < 3; ++nf) {
            bf16x8 bfv = *(const bf16x8*)(sB + ((nf0 + nf) * 16 + l16) * 200 + kc * 32 + lq * 8);
            acc[nf] = __builtin_amdgcn_mfma_f32_16x16x32_bf16(afr[kc], bfv, acc[nf], 0, 0, 0);
        }
    const long orow0 = rowbase + mi * 16 + lq * 4;
#pragma unroll
    for (int nf = 0; nf < 3; ++nf) {
        int col = nh * 96 + (nf0 + nf) * 16 + l16;
        float bv = BIAS ? bias[col] : 0.f;
#pragma unroll
        for (int j = 0; j < 4; ++j) {
            float val = acc[nf][j] + bv;
            long idx = (orow0 + j) * NOUT + col;
            if (OUTBF16) ((__bf16*)Out)[idx] = (__bf16)val;
            else ((float*)Out)[idx] = val;
        }
    }
}

// ---------------- K5: fused CPE(3x3 dw) + attn@v^T, 2 heads per pass ----------------
// thread = 2 adjacent tokens; pass hp handles 24 channels (heads 2hp, 2hp+1);
// tap loads = 3 aligned bf16x8; sW/sA2 reads are wave-uniform (LDS broadcast).
__global__ __launch_bounds__(256) void k_avcpe(const __bf16* __restrict__ v,
                                               const float* __restrict__ attn,
                                               const float* __restrict__ cw,
                                               const float* __restrict__ cb,
                                               __bf16* __restrict__ O) {
    __shared__ float sA2[NHEAD * HDIM * CRHD];
    __shared__ float sW[CRDIM * 9];
    __shared__ float sB2[CRDIM];
    int chunk = blockIdx.x, b = blockIdx.y, tid = threadIdx.x;
    for (int i = tid; i < NHEAD * HDIM * CRHD; i += 256)
        sA2[i] = attn[b * NHEAD * HDIM * CRHD + i];
    for (int i = tid; i < CRDIM * 9; i += 256) sW[i] = cw[i];
    if (tid < CRDIM) sB2[tid] = cb[tid];
    __syncthreads();
    int n0 = (chunk * 256 + tid) * 2;
    int y = n0 >> 7, x = n0 & 127;
    bool xm = (x > 0), xp = (x + 2 < WIMG);
    const __bf16* vb = v + (long)b * NTOK * CRDIM;
    __bf16* ob = O + (long)b * (CDIM * NTOK);
#pragma unroll
    for (int hp = 0; hp < 4; ++hp) {
        const int cb0 = hp * 24;
        float vp0[24], vp1[24];
#pragma unroll
        for (int j = 0; j < 24; ++j) { vp0[j] = sB2[cb0 + j]; vp1[j] = vp0[j]; }
#pragma unroll
        for (int rr = 0; rr < 3; ++rr) {
            int ry = y + rr - 1;
            if (ry < 0 || ry >= HIMG) continue;   // wave-uniform
            const __bf16* rowp = vb + ((long)ry * WIMG) * CRDIM + cb0;
#pragma unroll
            for (int cc = 0; cc < 4; ++cc) {
                int cx = x + cc - 1;
                bool valid = (cc > 0 || xm) && (cc < 3 || xp);
                float tv[24];
                if (valid) {
                    const __bf16* p = rowp + (long)cx * CRDIM;
                    bf16x8 t0 = *(const bf16x8*)(p);
                    bf16x8 t1 = *(const bf16x8*)(p + 8);
                    bf16x8 t2 = *(const bf16x8*)(p + 16);
#pragma unroll
                    for (int e = 0; e < 8; ++e) {
                        tv[e] = (float)t0[e]; tv[8 + e] = (float)t1[e]; tv[16 + e] = (float)t2[e];
                    }
                } else {
#pragma unroll
                    for (int e = 0; e < 24; ++e) tv[e] = 0.f;
                }
                if (cc < 3) {
                    int tap = rr * 3 + cc;
#pragma unroll
                    for (int j = 0; j < 24; ++j) vp0[j] += sW[(cb0 + j) * 9 + tap] * tv[j];
                    if (rr == 1 && cc == 1)
#pragma unroll
                        for (int j = 0; j < 24; ++j) vp0[j] += tv[j];   // + v itself
                }
                if (cc > 0) {
                    int tap = rr * 3 + cc - 1;
#pragma unroll
                    for (int j = 0; j < 24; ++j) vp1[j] += sW[(cb0 + j) * 9 + tap] * tv[j];
                    if (rr == 1 && cc == 2)
#pragma unroll
                        for (int j = 0; j < 24; ++j) vp1[j] += tv[j];
                }
            }
        }
#pragma unroll
        for (int hh = 0; hh < 2; ++hh) {
            int h = hp * 2 + hh;
            const float* ar = sA2 + h * HDIM * CRHD;
#pragma unroll
            for (int d = 0; d < HDIM; ++d) {
                float s0 = 0.f, s1 = 0.f;
#pragma unroll
                for (int e = 0; e < CRHD; ++e) {
                    float a = ar[d * CRHD + e];
                    s0 += a * vp0[hh * CRHD + e]; s1 += a * vp1[hh * CRHD + e];
                }
                bf16x2 o2; o2[0] = (__bf16)s0; o2[1] = (__bf16)s1;
                *(bf16x2*)(ob + (long)(d * NHEAD + h) * NTOK + n0) = o2;
            }
        }
    }
}

extern "C" void kernel_launch(void* const* d_in, const int* in_sizes, int n_in,
                              void* d_out, int out_size, void* d_ws, size_t ws_size,
                              hipStream_t stream) {
    const float* x      = (const float*)d_in[0];
    const float* red_w  = (const float*)d_in[3];
    const float* red_b  = (const float*)d_in[4];
    const float* dw_w   = (const float*)d_in[5];
    const float* dw_b   = (const float*)d_in[6];
    const float* conv_w = (const float*)d_in[7];
    const float* conv_b = (const float*)d_in[8];
    const float* ln_g   = (const float*)d_in[9];
    const float* ln_b   = (const float*)d_in[10];
    const float* q_w    = (const float*)d_in[11];
    const float* k_w    = (const float*)d_in[12];
    const float* v_w    = (const float*)d_in[13];
    const float* cpe_w  = (const float*)d_in[14];
    const float* cpe_b  = (const float*)d_in[15];
    const float* proj_w = (const float*)d_in[16];
    const float* proj_b = (const float*)d_in[17];
    float* out = (float*)d_out;

    char* ws = (char*)d_ws;
    __bf16* wb_v = (__bf16*)ws;                       // 36864 B
    __bf16* wb_p = (__bf16*)(ws + 36864);             // 73728 B
    float*  y1   = (float*)(ws + 110592);             // 786432 B
    float*  xr   = (float*)(ws + 897024);             // 786432 B
    float*  attn = (float*)(ws + 1683456);            // 147456 B
    __bf16* v    = (__bf16*)(ws + 1830912);           // 50331648 B
    __bf16* O    = (__bf16*)(ws + 52162560);          // 100663296 B

    k_prep<<<216, 256, 0, stream>>>(v_w, proj_w, wb_v);
    k_reduce<<<1024, 192, 0, stream>>>(x, red_w, red_b, y1);
    k_dwmix<<<dim3(64, 16), 192, 0, stream>>>(y1, dw_w, dw_b, conv_w, conv_b, ln_g, ln_b, xr);
    k_qkattn<<<dim3(8, 16), 256, 0, stream>>>(xr, q_w, k_w, attn);
    k_gemm<CRDIM, 1, false, true, false><<<4096, 512, 0, stream>>>(x, wb_v, nullptr, v);
    k_avcpe<<<dim3(32, 16), 256, 0, stream>>>(v, attn, cpe_w, cpe_b, O);
    k_gemm<CDIM, 2, true, false, true><<<8192, 512, 0, stream>>>(O, wb_p, proj_b, out);
}